// Round 3
// baseline (582.726 us; speedup 1.0000x reference)
//
#include <hip/hip_runtime.h>
#include <math.h>

#define KBINS 8
#define R_MIN -5.0f
#define R_MAX 5.0f
#define MIN_BIN 1e-4f
#define MIN_SLOPE 1e-4f

typedef float v4f __attribute__((ext_vector_type(4)));

// Single fused kernel. Each block's thread 0 recomputes the (tiny) param
// tables into LDS; all other waves wait at one __syncthreads. This removes
// the separate 1-block params kernel that serialized the whole device.
//
// LDS float layout (sb):
// [0..95]   per-bin padded table, 12 floats (48 B) per bin, bin b at 12b:
//           {x_k, 1/width, y_k, height, s, slope_k, slope_k1, pad...}
//           48 B stride => q0 reads hit bank groups {0,12,24,4,16,28,8,20}
//           (each 4 consecutive banks) for b=0..7 — a perfect partition of
//           the 32 banks; q1 (+16 B) likewise. The per-lane indexed
//           ds_read_b128 pair is bank-conflict-free for any mix of b.
// [96..102] interior edges e1..e7
// [104]     slopes[0]   [105] slopes[K]
// [106]     log(slopes[0])  [107] log(slopes[K])

__device__ __forceinline__ void rqs_elem(
        float x, const float* __restrict__ sb,
        float e1, float e2, float e3, float e4, float e5, float e6, float e7,
        float sl0, float slK, float lsl0, float lslK,
        float& y_out, float& ld_out) {
    // searchsorted(x_pos[1:-1], x, 'right') == count(edge <= x)
    int b = (int)(x >= e1) + (int)(x >= e2) + (int)(x >= e3) + (int)(x >= e4)
          + (int)(x >= e5) + (int)(x >= e6) + (int)(x >= e7);

    const float* q = sb + b * 12;
    const v4f q0 = *(const v4f*)q;          // {x_k, 1/w, y_k, h}
    const v4f q1 = *(const v4f*)(q + 4);    // {s, sk, sk1, pad}

    float xi = (x - q0[0]) * q0[1];
    xi = fminf(fmaxf(xi, 0.f), 1.f);
    const float s = q1[0], sk = q1[1], sk1 = q1[2];
    const float xi1m = 1.f - xi;
    const float xx = xi * xi1m;
    const float num  = s * xi * xi + sk * xx;
    const float den  = s + (sk1 + sk - 2.f * s) * xx;
    const float invd = __builtin_amdgcn_rcpf(den);   // v_rcp_f32, ~1 ulp
    float y = q0[2] + q0[3] * num * invd;
    const float dnum  = s * s * (sk1 * xi * xi + 2.f * s * xx + sk * xi1m * xi1m);
    const float deriv = dnum * invd * invd;
    float ld = __logf(deriv);

    const bool below = x < R_MIN;
    const bool above = x > R_MAX;
    const float yl = (x - R_MIN) * sl0 + R_MIN;
    const float yr = (x - R_MAX) * slK + R_MAX;
    y  = above ? yr  : y;
    y  = below ? yl  : y;
    ld = above ? lslK : ld;
    ld = below ? lsl0 : ld;

    y_out = y;
    ld_out = ld;
}

#define ELEMS_PER_BLOCK 1024   // 256 threads x 4 float4

__global__ __launch_bounds__(256) void rqs_fused(
        const v4f* __restrict__ x4,
        const float* __restrict__ p,
        v4f* __restrict__ y4,
        v4f* __restrict__ ld4,
        int n4) {
    __shared__ __align__(16) float sb[112];

    const int tid = threadIdx.x;
    if (tid == 0) {
        float w[KBINS], h[KBINS], sl[KBINS + 1];
        const float scale = (R_MAX - R_MIN) - KBINS * MIN_BIN;

        float m = -1e30f;
        #pragma unroll
        for (int i = 0; i < KBINS; ++i) m = fmaxf(m, p[i]);
        float sum = 0.f;
        #pragma unroll
        for (int i = 0; i < KBINS; ++i) { w[i] = expf(p[i] - m); sum += w[i]; }
        #pragma unroll
        for (int i = 0; i < KBINS; ++i) w[i] = w[i] / sum * scale + MIN_BIN;

        m = -1e30f;
        #pragma unroll
        for (int i = 0; i < KBINS; ++i) m = fmaxf(m, p[KBINS + i]);
        sum = 0.f;
        #pragma unroll
        for (int i = 0; i < KBINS; ++i) { h[i] = expf(p[KBINS + i] - m); sum += h[i]; }
        #pragma unroll
        for (int i = 0; i < KBINS; ++i) h[i] = h[i] / sum * scale + MIN_BIN;

        const float off = logf(expf(1.0f - MIN_SLOPE) - 1.0f);
        #pragma unroll
        for (int i = 0; i <= KBINS; ++i) {
            float z = p[2 * KBINS + i] + off;
            float sp = (z > 20.f) ? z : log1pf(expf(z));
            sl[i] = sp + MIN_SLOPE;
        }

        float xp[KBINS + 1], yp[KBINS + 1];
        xp[0] = R_MIN; yp[0] = R_MIN;
        #pragma unroll
        for (int i = 0; i < KBINS; ++i) { xp[i + 1] = xp[i] + w[i]; yp[i + 1] = yp[i] + h[i]; }

        #pragma unroll
        for (int b = 0; b < KBINS; ++b) {
            float* q = sb + b * 12;
            q[0] = xp[b];
            q[1] = 1.0f / w[b];
            q[2] = yp[b];
            q[3] = h[b];
            q[4] = h[b] / w[b];
            q[5] = sl[b];
            q[6] = sl[b + 1];
            q[7] = 0.f;
        }
        #pragma unroll
        for (int i = 0; i < 7; ++i) sb[96 + i] = xp[i + 1];
        sb[104] = sl[0];
        sb[105] = sl[KBINS];
        sb[106] = logf(sl[0]);
        sb[107] = logf(sl[KBINS]);
    }
    __syncthreads();

    const float e1 = sb[96], e2 = sb[97], e3 = sb[98], e4 = sb[99],
                e5 = sb[100], e6 = sb[101], e7 = sb[102];
    const float sl0 = sb[104], slK = sb[105];
    const float lsl0 = sb[106], lslK = sb[107];

    const int base = blockIdx.x * (ELEMS_PER_BLOCK / 4) + tid;

    if (base + 3 * 256 < n4) {
        // fast path: all four block-strided float4 in range; issue all loads first
        v4f xv0 = x4[base];
        v4f xv1 = x4[base + 256];
        v4f xv2 = x4[base + 512];
        v4f xv3 = x4[base + 768];

        #pragma unroll
        for (int g = 0; g < 4; ++g) {
            const v4f xv = (g == 0) ? xv0 : (g == 1) ? xv1 : (g == 2) ? xv2 : xv3;
            v4f yv, lv;
            #pragma unroll
            for (int j = 0; j < 4; ++j) {
                float yt, lt;
                rqs_elem(xv[j], sb, e1, e2, e3, e4, e5, e6, e7,
                         sl0, slK, lsl0, lslK, yt, lt);
                yv[j] = yt; lv[j] = lt;
            }
            const int i = base + g * 256;
            y4[i]  = yv;
            ld4[i] = lv;
        }
    } else {
        #pragma unroll
        for (int g = 0; g < 4; ++g) {
            const int i = base + g * 256;
            if (i >= n4) continue;
            const v4f xv = x4[i];
            v4f yv, lv;
            #pragma unroll
            for (int j = 0; j < 4; ++j) {
                float yt, lt;
                rqs_elem(xv[j], sb, e1, e2, e3, e4, e5, e6, e7,
                         sl0, slK, lsl0, lslK, yt, lt);
                yv[j] = yt; lv[j] = lt;
            }
            y4[i]  = yv;
            ld4[i] = lv;
        }
    }
}

extern "C" void kernel_launch(void* const* d_in, const int* in_sizes, int n_in,
                              void* d_out, int out_size, void* d_ws, size_t ws_size,
                              hipStream_t stream) {
    const float* x = (const float*)d_in[0];
    const float* p = (const float*)d_in[1];
    float* out = (float*)d_out;
    const int N = in_sizes[0];
    const int n4 = N / 4;   // N = 33554432, divisible by 4

    const int nblk = (n4 + (ELEMS_PER_BLOCK / 4) - 1) / (ELEMS_PER_BLOCK / 4);
    rqs_fused<<<nblk, 256, 0, stream>>>(
        (const v4f*)x, p, (v4f*)out, (v4f*)out + n4, n4);
}

// Round 4
// 366.126 us; speedup vs baseline: 1.5916x; 1.5916x over previous
//
#include <hip/hip_runtime.h>
#include <math.h>

#define KBINS 8
#define R_MIN -5.0f
#define R_MAX 5.0f
#define MIN_BIN 1e-4f
#define MIN_SLOPE 1e-4f

typedef float v4f __attribute__((ext_vector_type(4)));

// Single fused kernel. Each block's thread 0 recomputes the (tiny) param
// tables into LDS; one __syncthreads. At nblk = n4/1024 = 8192 blocks the
// prologue (~3k serial cycles) is hidden under other resident blocks.
//
// LDS float layout (sb):
// [0..95]   per-bin padded table, 12 floats (48 B) per bin, bin b at 12b:
//           {x_k, 1/width, y_k, height, s, slope_k, slope_k1, pad...}
//           48 B stride => the two per-lane indexed ds_read_b128 hit a
//           perfect 32-bank partition for b=0..7 -> conflict-free for any
//           mix of b (verified: SQ_LDS_BANK_CONFLICT == 0 in round 3).
// [96..102] interior edges e1..e7
// [104]     slopes[0]   [105] slopes[K]
// [106]     log(slopes[0])  [107] log(slopes[K])

__device__ __forceinline__ void rqs_elem(
        float x, const float* __restrict__ sb,
        float e1, float e2, float e3, float e4, float e5, float e6, float e7,
        float sl0, float slK, float lsl0, float lslK,
        float& y_out, float& ld_out) {
    // searchsorted(x_pos[1:-1], x, 'right') == count(edge <= x)
    int b = (int)(x >= e1) + (int)(x >= e2) + (int)(x >= e3) + (int)(x >= e4)
          + (int)(x >= e5) + (int)(x >= e6) + (int)(x >= e7);

    const float* q = sb + b * 12;
    const v4f q0 = *(const v4f*)q;          // {x_k, 1/w, y_k, h}
    const v4f q1 = *(const v4f*)(q + 4);    // {s, sk, sk1, pad}

    float xi = (x - q0[0]) * q0[1];
    xi = fminf(fmaxf(xi, 0.f), 1.f);
    const float s = q1[0], sk = q1[1], sk1 = q1[2];
    const float xi1m = 1.f - xi;
    const float xx = xi * xi1m;
    const float num  = s * xi * xi + sk * xx;
    const float den  = s + (sk1 + sk - 2.f * s) * xx;
    const float invd = __builtin_amdgcn_rcpf(den);   // v_rcp_f32, ~1 ulp
    float y = q0[2] + q0[3] * num * invd;
    const float dnum  = s * s * (sk1 * xi * xi + 2.f * s * xx + sk * xi1m * xi1m);
    const float deriv = dnum * invd * invd;
    float ld = __logf(deriv);

    const bool below = x < R_MIN;
    const bool above = x > R_MAX;
    const float yl = (x - R_MIN) * sl0 + R_MIN;
    const float yr = (x - R_MAX) * slK + R_MAX;
    y  = above ? yr  : y;
    y  = below ? yl  : y;
    ld = above ? lslK : ld;
    ld = below ? lsl0 : ld;

    y_out = y;
    ld_out = ld;
}

#define F4_PER_BLOCK 1024   // 256 threads x 4 float4 each, disjoint per block

__global__ __launch_bounds__(256) void rqs_fused(
        const v4f* __restrict__ x4,
        const float* __restrict__ p,
        v4f* __restrict__ y4,
        v4f* __restrict__ ld4,
        int n4) {
    __shared__ __align__(16) float sb[112];

    const int tid = threadIdx.x;
    if (tid == 0) {
        float w[KBINS], h[KBINS], sl[KBINS + 1];
        const float scale = (R_MAX - R_MIN) - KBINS * MIN_BIN;

        float m = -1e30f;
        #pragma unroll
        for (int i = 0; i < KBINS; ++i) m = fmaxf(m, p[i]);
        float sum = 0.f;
        #pragma unroll
        for (int i = 0; i < KBINS; ++i) { w[i] = expf(p[i] - m); sum += w[i]; }
        #pragma unroll
        for (int i = 0; i < KBINS; ++i) w[i] = w[i] / sum * scale + MIN_BIN;

        m = -1e30f;
        #pragma unroll
        for (int i = 0; i < KBINS; ++i) m = fmaxf(m, p[KBINS + i]);
        sum = 0.f;
        #pragma unroll
        for (int i = 0; i < KBINS; ++i) { h[i] = expf(p[KBINS + i] - m); sum += h[i]; }
        #pragma unroll
        for (int i = 0; i < KBINS; ++i) h[i] = h[i] / sum * scale + MIN_BIN;

        const float off = logf(expf(1.0f - MIN_SLOPE) - 1.0f);
        #pragma unroll
        for (int i = 0; i <= KBINS; ++i) {
            float z = p[2 * KBINS + i] + off;
            float sp = (z > 20.f) ? z : log1pf(expf(z));
            sl[i] = sp + MIN_SLOPE;
        }

        float xp[KBINS + 1], yp[KBINS + 1];
        xp[0] = R_MIN; yp[0] = R_MIN;
        #pragma unroll
        for (int i = 0; i < KBINS; ++i) { xp[i + 1] = xp[i] + w[i]; yp[i + 1] = yp[i] + h[i]; }

        #pragma unroll
        for (int b = 0; b < KBINS; ++b) {
            float* q = sb + b * 12;
            q[0] = xp[b];
            q[1] = 1.0f / w[b];
            q[2] = yp[b];
            q[3] = h[b];
            q[4] = h[b] / w[b];
            q[5] = sl[b];
            q[6] = sl[b + 1];
            q[7] = 0.f;
        }
        #pragma unroll
        for (int i = 0; i < 7; ++i) sb[96 + i] = xp[i + 1];
        sb[104] = sl[0];
        sb[105] = sl[KBINS];
        sb[106] = logf(sl[0]);
        sb[107] = logf(sl[KBINS]);
    }
    __syncthreads();

    const float e1 = sb[96], e2 = sb[97], e3 = sb[98], e4 = sb[99],
                e5 = sb[100], e6 = sb[101], e7 = sb[102];
    const float sl0 = sb[104], slK = sb[105];
    const float lsl0 = sb[106], lslK = sb[107];

    const int base = blockIdx.x * F4_PER_BLOCK + tid;   // disjoint 1024-f4 range per block

    if (base + 3 * 256 < n4) {
        // fast path: all four block-strided float4 in range; issue all loads first
        v4f xv0 = x4[base];
        v4f xv1 = x4[base + 256];
        v4f xv2 = x4[base + 512];
        v4f xv3 = x4[base + 768];

        #pragma unroll
        for (int g = 0; g < 4; ++g) {
            const v4f xv = (g == 0) ? xv0 : (g == 1) ? xv1 : (g == 2) ? xv2 : xv3;
            v4f yv, lv;
            #pragma unroll
            for (int j = 0; j < 4; ++j) {
                float yt, lt;
                rqs_elem(xv[j], sb, e1, e2, e3, e4, e5, e6, e7,
                         sl0, slK, lsl0, lslK, yt, lt);
                yv[j] = yt; lv[j] = lt;
            }
            const int i = base + g * 256;
            y4[i]  = yv;
            ld4[i] = lv;
        }
    } else {
        #pragma unroll
        for (int g = 0; g < 4; ++g) {
            const int i = base + g * 256;
            if (i >= n4) continue;
            const v4f xv = x4[i];
            v4f yv, lv;
            #pragma unroll
            for (int j = 0; j < 4; ++j) {
                float yt, lt;
                rqs_elem(xv[j], sb, e1, e2, e3, e4, e5, e6, e7,
                         sl0, slK, lsl0, lslK, yt, lt);
                yv[j] = yt; lv[j] = lt;
            }
            y4[i]  = yv;
            ld4[i] = lv;
        }
    }
}

extern "C" void kernel_launch(void* const* d_in, const int* in_sizes, int n_in,
                              void* d_out, int out_size, void* d_ws, size_t ws_size,
                              hipStream_t stream) {
    const float* x = (const float*)d_in[0];
    const float* p = (const float*)d_in[1];
    float* out = (float*)d_out;
    const int N = in_sizes[0];
    const int n4 = N / 4;   // N = 33554432, divisible by 4

    const int nblk = (n4 + F4_PER_BLOCK - 1) / F4_PER_BLOCK;   // n4/1024 = 8192 exactly
    rqs_fused<<<nblk, 256, 0, stream>>>(
        (const v4f*)x, p, (v4f*)out, (v4f*)out + n4, n4);
}

// Round 5
// 354.920 us; speedup vs baseline: 1.6418x; 1.0316x over previous
//
#include <hip/hip_runtime.h>
#include <math.h>

#define KBINS 8
#define R_MIN -5.0f
#define R_MAX 5.0f
#define MIN_BIN 1e-4f
#define MIN_SLOPE 1e-4f

typedef float v4f __attribute__((ext_vector_type(4)));

// d_ws float layout:
// [0..8]    x_pos (9)   (ws[1..7] = interior edges; wave-uniform -> s_load)
// [9..17]   y_pos (9)
// [18..26]  slopes (9)
// [28..91]  per-bin table, 8 floats (32 B) per bin, bin b at 28+8b:
//           {x_k, 1/width, y_k, height, s, slope_k, slope_k1, c0=sk+sk1-2s}
//           32 B stride: bins b and b+4 alias the same bank quad -> worst
//           case 2-way LDS conflict, which is free on CDNA4 (m136: 1.02x).
// [92]      log(slopes[0])
// [93]      log(slopes[K])

__global__ void rqs_params_kernel(const float* __restrict__ p, float* __restrict__ ws) {
    if (threadIdx.x != 0 || blockIdx.x != 0) return;
    float w[KBINS], h[KBINS], sl[KBINS + 1];
    const float scale = (R_MAX - R_MIN) - KBINS * MIN_BIN;

    // softmax widths
    float m = -1e30f;
    for (int i = 0; i < KBINS; ++i) m = fmaxf(m, p[i]);
    float sum = 0.f;
    for (int i = 0; i < KBINS; ++i) { w[i] = expf(p[i] - m); sum += w[i]; }
    for (int i = 0; i < KBINS; ++i) w[i] = w[i] / sum * scale + MIN_BIN;

    // softmax heights
    m = -1e30f;
    for (int i = 0; i < KBINS; ++i) m = fmaxf(m, p[KBINS + i]);
    sum = 0.f;
    for (int i = 0; i < KBINS; ++i) { h[i] = expf(p[KBINS + i] - m); sum += h[i]; }
    for (int i = 0; i < KBINS; ++i) h[i] = h[i] / sum * scale + MIN_BIN;

    // softplus slopes
    const float off = logf(expf(1.0f - MIN_SLOPE) - 1.0f);
    for (int i = 0; i <= KBINS; ++i) {
        float z = p[2 * KBINS + i] + off;
        float sp = (z > 20.f) ? z : log1pf(expf(z));
        sl[i] = sp + MIN_SLOPE;
    }

    float xp[KBINS + 1], yp[KBINS + 1];
    xp[0] = R_MIN; yp[0] = R_MIN;
    for (int i = 0; i < KBINS; ++i) { xp[i + 1] = xp[i] + w[i]; yp[i + 1] = yp[i] + h[i]; }

    for (int i = 0; i <= KBINS; ++i) {
        ws[i] = xp[i];
        ws[9 + i] = yp[i];
        ws[18 + i] = sl[i];
    }
    for (int b = 0; b < KBINS; ++b) {
        float width  = xp[b + 1] - xp[b];
        float height = yp[b + 1] - yp[b];
        float s = height / width;
        float* q = ws + 28 + b * 8;
        q[0] = xp[b];
        q[1] = 1.0f / width;
        q[2] = yp[b];
        q[3] = height;
        q[4] = s;
        q[5] = sl[b];
        q[6] = sl[b + 1];
        q[7] = sl[b] + sl[b + 1] - 2.0f * s;   // c0, precomputed
    }
    ws[92] = logf(sl[0]);
    ws[93] = logf(sl[KBINS]);
}

__global__ __launch_bounds__(256) void rqs_main_kernel(
        const v4f* __restrict__ x4,
        const float*  __restrict__ ws,
        v4f* __restrict__ y4,
        v4f* __restrict__ ld4,
        int n4) {
    __shared__ __align__(16) v4f sbin[2 * KBINS];  // bin b: sbin[2b]={xk,invw,yk,h}, sbin[2b+1]={s,sk,sk1,c0}

    const int tid = threadIdx.x;
    if (tid < 2 * KBINS) sbin[tid] = ((const v4f*)(ws + 28))[tid];
    __syncthreads();

    const int i = blockIdx.x * blockDim.x + tid;
    if (i >= n4) return;

    // wave-uniform -> compiler scalarizes to s_load (as in the 355.7us baseline)
    const float e1 = ws[1], e2 = ws[2], e3 = ws[3], e4 = ws[4],
                e5 = ws[5], e6 = ws[6], e7 = ws[7];
    const float sl0 = ws[18], slK = ws[26];
    const float lsl0 = ws[92], lslK = ws[93];

    const v4f xv = x4[i];
    v4f yv, lv;

    #pragma unroll
    for (int j = 0; j < 4; ++j) {
        const float x = xv[j];
        // searchsorted(x_pos[1:-1], x, 'right') == count(edge <= x)
        int b = (int)(x >= e1) + (int)(x >= e2) + (int)(x >= e3) + (int)(x >= e4)
              + (int)(x >= e5) + (int)(x >= e6) + (int)(x >= e7);

        const v4f q0 = sbin[2 * b];
        const v4f q1 = sbin[2 * b + 1];

        float xi = (x - q0[0]) * q0[1];
        xi = fminf(fmaxf(xi, 0.f), 1.f);
        const float s = q1[0], sk = q1[1], sk1 = q1[2], c0 = q1[3];
        const float xi1m = 1.f - xi;
        const float xx   = xi * xi1m;
        const float xi2  = xi * xi;
        const float num  = s * xi2 + sk * xx;
        const float den  = s + c0 * xx;                 // c0 = sk+sk1-2s (precomputed)
        const float invd = __builtin_amdgcn_rcpf(den);  // v_rcp_f32, ~1 ulp; 0.03 absmax slack
        float y = q0[2] + q0[3] * (num * invd);
        const float dnum  = (s * s) * (sk1 * xi2 + 2.f * s * xx + sk * (xi1m * xi1m));
        const float deriv = dnum * (invd * invd);
        float ld = __logf(deriv);

        const bool below = x < R_MIN;
        const bool above = x > R_MAX;
        const float yl = (x - R_MIN) * sl0 + R_MIN;
        const float yr = (x - R_MAX) * slK + R_MAX;
        y  = above ? yr  : y;
        y  = below ? yl  : y;
        ld = above ? lslK : ld;
        ld = below ? lsl0 : ld;

        yv[j] = y;
        lv[j] = ld;
    }

    y4[i]  = yv;
    ld4[i] = lv;
}

extern "C" void kernel_launch(void* const* d_in, const int* in_sizes, int n_in,
                              void* d_out, int out_size, void* d_ws, size_t ws_size,
                              hipStream_t stream) {
    const float* x = (const float*)d_in[0];
    const float* p = (const float*)d_in[1];
    float* out = (float*)d_out;
    float* ws  = (float*)d_ws;
    const int N = in_sizes[0];
    const int n4 = N / 4;   // N = 33554432, divisible by 4

    rqs_params_kernel<<<1, 64, 0, stream>>>(p, ws);
    rqs_main_kernel<<<(n4 + 255) / 256, 256, 0, stream>>>(
        (const v4f*)x, ws, (v4f*)out, (v4f*)out + n4, n4);
}